// Round 1
// baseline (319.675 us; speedup 1.0000x reference)
//
#include <hip/hip_runtime.h>

#define NN 50000
#define EE 800000
#define DD 64
#define GG 512
#define TILES 782          // ceil(NN/64)
#define SCAN_BLOCKS 98     // ceil(NN/512)

typedef __attribute__((ext_vector_type(8))) short short8;
typedef __attribute__((ext_vector_type(4))) float f32x4;

// ---- bf16 helpers ----
__device__ __forceinline__ float b2f(unsigned short u) {
    union { unsigned int i; float f; } c;
    c.i = ((unsigned int)u) << 16;
    return c.f;
}
__device__ __forceinline__ unsigned short f2b(float f) {
    union { float f; unsigned int i; } c;
    c.f = f;
    const unsigned int r = c.i + 0x7FFFu + ((c.i >> 16) & 1u);  // rne
    return (unsigned short)(r >> 16);
}
__device__ __forceinline__ int rfl(int v) { return __builtin_amdgcn_readfirstlane(v); }

__device__ __forceinline__ void acc4(float* acc, ushort4 v) {
    acc[0] += b2f(v.x); acc[1] += b2f(v.y); acc[2] += b2f(v.z); acc[3] += b2f(v.w);
}

// ===========================================================================
// prep: x fp32 -> bf16 + all zeroing (counts, stats, xpool, zero-row) +
// weight swizzle (last 6 blocks).
// ===========================================================================
__global__ __launch_bounds__(256) void prep_kernel(const float* __restrict__ x,
                                                   unsigned short* __restrict__ xbf,
                                                   int* __restrict__ counts,
                                                   float* __restrict__ zblock,
                                                   const float* __restrict__ w0,
                                                   const float* __restrict__ w1,
                                                   const float* __restrict__ w2,
                                                   const float* __restrict__ w3,
                                                   const float* __restrict__ w4,
                                                   const float* __restrict__ w5,
                                                   unsigned short* __restrict__ wfrag) {
    if (blockIdx.x >= 3209) {   // weight swizzle: fp32 [k][n] -> B-frag order
        const float* ws[6] = {w0, w1, w2, w3, w4, w5};
        const int wi = blockIdx.x - 3209;
        const float* w = ws[wi];
        unsigned short* o = wfrag + wi * 4096;
        #pragma unroll
        for (int it = 0; it < 2; ++it) {
            const int idx = it * 256 + threadIdx.x;   // fid*64 + lane
            const int fid = idx >> 6, lane = idx & 63;
            const int kt = fid >> 2, nt = fid & 3;
            const int kbase = kt * 32 + (lane >> 4) * 8;
            const int n = nt * 16 + (lane & 15);
            #pragma unroll
            for (int j = 0; j < 8; ++j)
                o[idx * 8 + j] = f2b(w[(kbase + j) * 64 + n]);
        }
        return;
    }
    const int tid = blockIdx.x * 256 + threadIdx.x;
    if (tid < 800000) {
        const float4 v = ((const float4*)x)[tid];
        ushort4 o;
        o.x = f2b(v.x); o.y = f2b(v.y); o.z = f2b(v.z); o.w = f2b(v.w);
        ((ushort4*)xbf)[tid] = o;
    } else if (tid < 812500) {
        ((int4*)counts)[tid - 800000] = make_int4(0, 0, 0, 0);
    } else if (tid < 821468) {   // stats + xpool + 128B zero-row
        ((float4*)zblock)[tid - 812500] = make_float4(0.f, 0.f, 0.f, 0.f);
    }
}

// ===========================================================================
// CSR build: histogram -> 2-level exclusive scan -> XCD-partitioned fill.
// ===========================================================================
__global__ __launch_bounds__(256) void hist_kernel(const int* __restrict__ ei,
                                                   int* __restrict__ counts) {
    const int e = blockIdx.x * blockDim.x + threadIdx.x;
    if (e < EE) atomicAdd(&counts[ei[EE + e]], 1);
}

__global__ __launch_bounds__(512) void scan1_kernel(const int* __restrict__ counts,
                                                    int* __restrict__ scanned,
                                                    int* __restrict__ bsum) {
    __shared__ int buf[512];
    const int i = blockIdx.x * 512 + threadIdx.x;
    const int v = (i < NN) ? counts[i] : 0;
    buf[threadIdx.x] = v;
    __syncthreads();
    for (int off = 1; off < 512; off <<= 1) {
        const int add = (threadIdx.x >= off) ? buf[threadIdx.x - off] : 0;
        __syncthreads();
        buf[threadIdx.x] += add;
        __syncthreads();
    }
    if (i < NN) scanned[i] = buf[threadIdx.x] - v;   // exclusive
    if (threadIdx.x == 511) bsum[blockIdx.x] = buf[511];
}

__global__ __launch_bounds__(512) void scan2_kernel(const int* __restrict__ scanned,
                                                    const int* __restrict__ bsum,
                                                    int* __restrict__ rowptr,
                                                    int* __restrict__ cursor) {
    __shared__ int red[128];
    if (threadIdx.x < 128)
        red[threadIdx.x] = (threadIdx.x < blockIdx.x) ? bsum[threadIdx.x] : 0;
    __syncthreads();
    for (int off = 64; off > 0; off >>= 1) {
        if (threadIdx.x < off) red[threadIdx.x] += red[threadIdx.x + off];
        __syncthreads();
    }
    const int offset = red[0];
    const int i = blockIdx.x * 512 + threadIdx.x;
    if (i < NN) {
        const int p = scanned[i] + offset;
        rowptr[i] = p;
        cursor[i] = p;
    }
    if (blockIdx.x == 0 && threadIdx.x == 0) rowptr[NN] = EE;
}

// 8-class partitioned fill (round-16: reverted from 16 classes — the extra
// filtered re-reads of ei cost more than the smaller write regions saved;
// 8-class is the empirically best point).
__global__ __launch_bounds__(256) void fill_kernel(const int* __restrict__ ei,
                                                   int* __restrict__ cursor,
                                                   int* __restrict__ col) {
    const int cls = blockIdx.x & 7;
    const int chunk = blockIdx.x >> 3;              // 0..255
    const int e0 = chunk * 3125;                    // 256*3125 == EE
    for (int e = e0 + threadIdx.x; e < e0 + 3125; e += 256) {
        const int dst = ei[EE + e];
        if (dst / 6250 == cls) {
            const int pos = atomicAdd(&cursor[dst], 1);
            col[pos] = ei[e];
        }
    }
}

// ===========================================================================
// Gather: one wave per row. New lane geometry (round-17): sub=lane>>4 picks
// a neighbor slot, fg=lane&15 picks a 4-feature group. Each ushort4 load
// covers 4 neighbor rows (512B/instr, 4x fewer VMEM ops than 2B/lane);
// col indices come from ONE vector load distributed via __shfl; invalid
// slots read a dedicated 128B zero-row (pointer cndmask, no per-elem mask);
// cross-sub reduction via 2 shfl_xor stages. Register footprint ~50 VGPR ->
// 8 waves/SIMD for latency hiding. Previous layer's BN finalize folded into
// the preamble (scl/sft redistributed with 8 shuffles).
// z = scl.*(h_self + sum_nbr h) + (deg+1).*sft
// ===========================================================================
__global__ __launch_bounds__(256, 8) void gather_kernel(const unsigned short* __restrict__ hin,
                                                        const int* __restrict__ rowptr,
                                                        const int* __restrict__ col,
                                                        const float* __restrict__ stats,
                                                        const float* __restrict__ ga,
                                                        const float* __restrict__ be,
                                                        const int apply,
                                                        const unsigned short* __restrict__ zrow,
                                                        unsigned short* __restrict__ z) {
    const int wv = (blockIdx.x * 256 + threadIdx.x) >> 6;
    const int lane = threadIdx.x & 63;
    const int row = rfl(wv);
    if (row >= NN) return;
    const int sub = lane >> 4;          // neighbor slot 0..3
    const int fg = lane & 15;           // features fg*4 .. fg*4+3

    float scl[4], sft[4];
    if (apply) {   // folded finalize (1KB stats region, L2-hot)
        float s = 0.f, sq = 0.f;
        #pragma unroll
        for (int k = 0; k < 8; ++k) {
            s += stats[k * 128 + lane];
            sq += stats[k * 128 + 64 + lane];
        }
        const float mean = s * (1.0f / NN);
        const float var = sq * (1.0f / NN) - mean * mean;
        const float sc = ga[lane] * rsqrtf(var + 1e-5f);
        const float sf = be[lane] - mean * sc;
        #pragma unroll
        for (int j = 0; j < 4; ++j) {
            scl[j] = __shfl(sc, fg * 4 + j);
            sft[j] = __shfl(sf, fg * 4 + j);
        }
    } else {
        #pragma unroll
        for (int j = 0; j < 4; ++j) { scl[j] = 1.0f; sft[j] = 0.0f; }
    }

    const int beg = rfl(rowptr[row]);
    const int end = rfl(rowptr[row + 1]);
    const int deg = end - beg;

    float acc[4];
    {   // self term: sub 0 reads the row, other subs read the zero-row
        const unsigned short* ps = (sub == 0) ? (hin + row * 64) : zrow;
        const ushort4 sv = *(const ushort4*)(ps + fg * 4);
        acc[0] = b2f(sv.x); acc[1] = b2f(sv.y); acc[2] = b2f(sv.z); acc[3] = b2f(sv.w);
    }

    if (deg <= 16) {
        const int cv = col[beg + (lane & 15)];     // 64B broadcast load
        ushort4 hv[4];
        #pragma unroll
        for (int s = 0; s < 4; ++s) {
            const int n = s * 4 + sub;
            const int cr = __shfl(cv, n);
            const unsigned short* pr = (n < deg) ? (hin + cr * 64) : zrow;
            hv[s] = *(const ushort4*)(pr + fg * 4);
        }
        #pragma unroll
        for (int s = 0; s < 4; ++s) acc4(acc, hv[s]);
    } else if (deg <= 32) {
        const int cv = col[beg + (lane & 31)];     // 128B broadcast load
        ushort4 hv[8];
        #pragma unroll
        for (int s = 0; s < 8; ++s) {
            const int n = s * 4 + sub;
            const int cr = __shfl(cv, n);
            const unsigned short* pr = (n < deg) ? (hin + cr * 64) : zrow;
            hv[s] = *(const ushort4*)(pr + fg * 4);
        }
        #pragma unroll
        for (int s = 0; s < 8; ++s) acc4(acc, hv[s]);
    } else {
        int base = beg;
        for (; base + 32 <= end; base += 32) {     // full 32-neighbor chunks
            const int cv = col[base + (lane & 31)];
            ushort4 hv[8];
            #pragma unroll
            for (int s = 0; s < 8; ++s) {
                const int cr = __shfl(cv, s * 4 + sub);
                hv[s] = *(const ushort4*)(hin + cr * 64 + fg * 4);
            }
            #pragma unroll
            for (int s = 0; s < 8; ++s) acc4(acc, hv[s]);
        }
        if (base < end) {                          // masked tail (<32)
            const int rem = end - base;
            const int cv = col[base + (lane & 31)];
            ushort4 hv[8];
            #pragma unroll
            for (int s = 0; s < 8; ++s) {
                const int n = s * 4 + sub;
                const int cr = __shfl(cv, n);
                const unsigned short* pr = (n < rem) ? (hin + cr * 64) : zrow;
                hv[s] = *(const ushort4*)(pr + fg * 4);
            }
            #pragma unroll
            for (int s = 0; s < 8; ++s) acc4(acc, hv[s]);
        }
    }

    // reduce across the 4 sub groups (lanes fg, fg+16, fg+32, fg+48)
    #pragma unroll
    for (int j = 0; j < 4; ++j) {
        acc[j] += __shfl_xor(acc[j], 16);
        acc[j] += __shfl_xor(acc[j], 32);
    }

    if (sub == 0) {
        const float dsft = (float)(deg + 1);
        ushort4 o;
        o.x = f2b(fmaf(acc[0], scl[0], dsft * sft[0]));
        o.y = f2b(fmaf(acc[1], scl[1], dsft * sft[1]));
        o.z = f2b(fmaf(acc[2], scl[2], dsft * sft[2]));
        o.w = f2b(fmaf(acc[3], scl[3], dsft * sft[3]));
        *(ushort4*)(z + row * 64 + fg * 4) = o;
    }
}

// ===========================================================================
// MFMA MLP: 64-row block, 4 waves; wave computes its 16x64 strip with
// mfma_f32_16x16x32_bf16. launch_bounds(256,2) keeps wA/wB register-resident.
// No fences/tickets (round-11 lesson).
// ===========================================================================
__global__ __launch_bounds__(256, 2) void mlp_kernel(const unsigned short* __restrict__ z,
                                                     const unsigned short* __restrict__ wfa,
                                                     const float* __restrict__ ba,
                                                     const unsigned short* __restrict__ wfb,
                                                     const float* __restrict__ bb,
                                                     unsigned short* __restrict__ tout,
                                                     float* __restrict__ stats) {
    __shared__ unsigned short ldsT[4][16][72];   // per-wave transpose tiles
    __shared__ float red[512];

    const int wave = threadIdx.x >> 6;
    const int lane = threadIdx.x & 63;
    const int quad = lane >> 4;
    const int l15 = lane & 15;
    const int rowbase = blockIdx.x * 64 + wave * 16;
    const bool valid = rowbase < NN;

    short8 wA[8], wB[8];
    #pragma unroll
    for (int f = 0; f < 8; ++f) {
        wA[f] = *(const short8*)(wfa + (f * 64 + lane) * 8);
        wB[f] = *(const short8*)(wfb + (f * 64 + lane) * 8);
    }
    float biasA[4], biasB[4];
    #pragma unroll
    for (int nt = 0; nt < 4; ++nt) {
        biasA[nt] = ba[nt * 16 + l15];
        biasB[nt] = bb[nt * 16 + l15];
    }

    const int arow = valid ? (rowbase + l15) : 0;
    const short8 a0 = *(const short8*)(z + arow * 64 + quad * 8);
    const short8 a1 = *(const short8*)(z + arow * 64 + 32 + quad * 8);

    f32x4 acc[4];
    #pragma unroll
    for (int nt = 0; nt < 4; ++nt) {
        f32x4 c = {0.f, 0.f, 0.f, 0.f};
        c = __builtin_amdgcn_mfma_f32_16x16x32_bf16(a0, wA[nt], c, 0, 0, 0);
        c = __builtin_amdgcn_mfma_f32_16x16x32_bf16(a1, wA[4 + nt], c, 0, 0, 0);
        acc[nt] = c;
    }
    #pragma unroll
    for (int nt = 0; nt < 4; ++nt)
        #pragma unroll
        for (int r = 0; r < 4; ++r)
            ldsT[wave][quad * 4 + r][nt * 16 + l15] =
                f2b(fmaxf(acc[nt][r] + biasA[nt], 0.f));

    const short8 y0 = *(const short8*)(&ldsT[wave][l15][quad * 8]);
    const short8 y1 = *(const short8*)(&ldsT[wave][l15][32 + quad * 8]);

    #pragma unroll
    for (int nt = 0; nt < 4; ++nt) {
        f32x4 c = {0.f, 0.f, 0.f, 0.f};
        c = __builtin_amdgcn_mfma_f32_16x16x32_bf16(y0, wB[nt], c, 0, 0, 0);
        c = __builtin_amdgcn_mfma_f32_16x16x32_bf16(y1, wB[4 + nt], c, 0, 0, 0);
        acc[nt] = c;
    }
    #pragma unroll
    for (int nt = 0; nt < 4; ++nt)
        #pragma unroll
        for (int r = 0; r < 4; ++r)
            ldsT[wave][quad * 4 + r][nt * 16 + l15] =
                f2b(fmaxf(acc[nt][r] + biasB[nt], 0.f));

    // BN partials (wave reads its own region; same-wave ordered)
    {
        float s = 0.f, sq = 0.f;
        if (valid) {
            #pragma unroll 4
            for (int r = 0; r < 16; ++r) {
                const float v = b2f(ldsT[wave][r][lane]);
                s += v;
                sq += v * v;
            }
        }
        red[wave * 128 + lane] = s;
        red[wave * 128 + 64 + lane] = sq;
    }
    __syncthreads();

    if (threadIdx.x < 128) {
        const float tot = red[threadIdx.x] + red[128 + threadIdx.x] +
                          red[256 + threadIdx.x] + red[384 + threadIdx.x];
        atomicAdd(&stats[(blockIdx.x & 7) * 128 + threadIdx.x], tot);
    }

    #pragma unroll
    for (int m = 0; m < 4; ++m) {
        const int g = m * 256 + threadIdx.x;     // 1024 groups of 4 feats
        const int r = g >> 4;
        const int f4 = (g & 15) * 4;
        const int grow = blockIdx.x * 64 + r;
        if (grow < NN)
            *(ushort4*)(tout + grow * 64 + f4) =
                *(const ushort4*)(&ldsT[r >> 4][r & 15][f4]);
    }
}

// ===========================================================================
// Pool (bf16 t in, layer-3 BN finalize folded into preamble); batch sorted.
// ===========================================================================
__global__ __launch_bounds__(256) void pool_kernel(const unsigned short* __restrict__ t,
                                                   const int* __restrict__ batch,
                                                   const float* __restrict__ stats,
                                                   const float* __restrict__ ga,
                                                   const float* __restrict__ be,
                                                   float* __restrict__ xpool) {
    const int wv = (blockIdx.x * 256 + threadIdx.x) >> 6;
    const int lane = threadIdx.x & 63;

    float s = 0.f, sq = 0.f;
    #pragma unroll
    for (int k = 0; k < 8; ++k) {
        s += stats[k * 128 + lane];
        sq += stats[k * 128 + 64 + lane];
    }
    const float mean = s * (1.0f / NN);
    const float var = sq * (1.0f / NN) - mean * mean;
    const float scl = ga[lane] * rsqrtf(var + 1e-5f);
    const float sft = be[lane] - mean * scl;

    const int r0 = wv * 64;
    if (r0 >= NN) return;
    const int r1 = min(r0 + 64, NN);
    int gprev = batch[r0];
    float acc = 0.f;
    for (int r = r0; r < r1; ++r) {
        const int g = batch[r];
        if (g != gprev) {
            __hip_atomic_fetch_add(&xpool[gprev * 64 + lane], acc,
                                   __ATOMIC_RELAXED, __HIP_MEMORY_SCOPE_AGENT);
            acc = 0.f;
            gprev = g;
        }
        acc += fmaf(b2f(t[r * 64 + lane]), scl, sft);
    }
    __hip_atomic_fetch_add(&xpool[gprev * 64 + lane], acc,
                           __ATOMIC_RELAXED, __HIP_MEMORY_SCOPE_AGENT);
}

// ===========================================================================
// Fused head: out[g] = relu((xpool[g] @ w0 + b0) @ w1 + b1). One block per g.
// ===========================================================================
__global__ __launch_bounds__(128) void head_kernel(const float* __restrict__ xpool,
                                                   const float* __restrict__ w0,
                                                   const float* __restrict__ b0,
                                                   const float* __restrict__ w1,
                                                   const float* __restrict__ b1,
                                                   float* __restrict__ out) {
    __shared__ float xp[64];
    __shared__ float midl[128];
    const int g = blockIdx.x;
    const int t = threadIdx.x;
    if (t < 64) xp[t] = xpool[g * 64 + t];
    __syncthreads();
    float acc = b0[t];
    #pragma unroll 8
    for (int k = 0; k < 64; ++k) acc = fmaf(xp[k], w0[k * 128 + t], acc);
    midl[t] = acc;
    __syncthreads();
    if (t < 64) {
        float a2 = b1[t];
        #pragma unroll 8
        for (int k = 0; k < 128; ++k) a2 = fmaf(midl[k], w1[k * 64 + t], a2);
        out[g * 64 + t] = fmaxf(a2, 0.f);
    }
}

extern "C" void kernel_launch(void* const* d_in, const int* in_sizes, int n_in,
                              void* d_out, int out_size, void* d_ws, size_t ws_size,
                              hipStream_t stream) {
    const float* x = (const float*)d_in[0];
    const int* ei = (const int*)d_in[1];
    const int* batch = (const int*)d_in[2];

    // ---- workspace layout ----
    int* ibase   = (int*)d_ws;
    int* counts  = ibase;            // 50000 (int4-zeroable)
    int* scanned = ibase + 50000;    // 50000
    int* rowptr  = ibase + 100000;   // 50001 (pad to 50004)
    int* cursor  = ibase + 150004;   // 50000
    int* bsum    = ibase + 200004;   // 128 (98 used)
    int* col     = ibase + 200132;   // 800000 -> int end 1,000,132 (pad 1,000,192)
    float* fbase = (float*)d_ws + 1000192;       // 16B aligned
    float* stats = fbase;                        // 3 x 1024 = 3072
    float* xpool = stats + 3072;                 // 32768 (zeroed by prep)
    const unsigned short* zrow = (const unsigned short*)(fbase + 35840);  // 128B zero-row
    unsigned short* zbf  = (unsigned short*)(fbase + 35856 + 128);  // NN*64
    unsigned short* xbf  = zbf + 3200000;
    unsigned short* t0bf = xbf + 3200000;
    unsigned short* t1bf = t0bf + 3200000;
    unsigned short* wfrag = t1bf + 3200000;      // 6 x 4096 bf16

    // ---- prep (x->bf16 + zeroing + weight swizzle) + CSR build ----
    prep_kernel<<<3215, 256, 0, stream>>>(x, xbf, counts, stats,
                                          (const float*)d_in[3], (const float*)d_in[5],
                                          (const float*)d_in[9], (const float*)d_in[11],
                                          (const float*)d_in[15], (const float*)d_in[17],
                                          wfrag);
    hist_kernel<<<(EE + 255) / 256, 256, 0, stream>>>(ei, counts);
    scan1_kernel<<<SCAN_BLOCKS, 512, 0, stream>>>(counts, scanned, bsum);
    scan2_kernel<<<SCAN_BLOCKS, 512, 0, stream>>>(scanned, bsum, rowptr, cursor);
    fill_kernel<<<2048, 256, 0, stream>>>(ei, cursor, col);

    // ---- 3 GIN layers: gather (folded finalize) + MFMA mlp ----
    const unsigned short* hcur = xbf;
    unsigned short* touts[3] = {t0bf, t1bf, t0bf};
    for (int l = 0; l < 3; ++l) {
        const float* ba = (const float*)d_in[3 + l * 6 + 1];
        const float* bb = (const float*)d_in[3 + l * 6 + 3];
        const float* gp = (const float*)d_in[3 + (l ? (l - 1) : 0) * 6 + 4];
        const float* bp = (const float*)d_in[3 + (l ? (l - 1) : 0) * 6 + 5];

        gather_kernel<<<12500, 256, 0, stream>>>(hcur, rowptr, col,
                                                 stats + (l ? (l - 1) : 0) * 1024,
                                                 gp, bp, l > 0, zrow, zbf);
        mlp_kernel<<<TILES, 256, 0, stream>>>(zbf,
                                              wfrag + (l * 2 + 0) * 4096, ba,
                                              wfrag + (l * 2 + 1) * 4096, bb,
                                              touts[l], stats + l * 1024);
        hcur = touts[l];
    }

    pool_kernel<<<(TILES + 3) / 4, 256, 0, stream>>>(
        t0bf, batch, stats + 2048,
        (const float*)d_in[19], (const float*)d_in[20], xpool);
    head_kernel<<<GG, 128, 0, stream>>>(
        xpool, (const float*)d_in[21], (const float*)d_in[22],
        (const float*)d_in[23], (const float*)d_in[24], (float*)d_out);
}